// Round 1
// baseline (394.662 us; speedup 1.0000x reference)
//
#include <hip/hip_runtime.h>
#include <math.h>

typedef __attribute__((ext_vector_type(8))) short short8;
typedef __attribute__((ext_vector_type(4))) float f32x4;
typedef __attribute__((ext_vector_type(4))) unsigned short ushort4v;

#define AS1 __attribute__((address_space(1)))
#define AS3 __attribute__((address_space(3)))
#define GLOAD16(src, dst) __builtin_amdgcn_global_load_lds((const AS1 void*)(src), (AS3 void*)(dst), 16, 0, 0)

__device__ __forceinline__ unsigned short f2b(float f) {
    union { float f; unsigned int u; } c; c.f = f;
    return (unsigned short)((c.u + 0x7FFFu + ((c.u >> 16) & 1u)) >> 16);
}
__device__ __forceinline__ float b2f(unsigned short u) {
    union { unsigned int u; float f; } c; c.u = ((unsigned int)u) << 16;
    return c.f;
}

// ---------------- fp32 -> bf16 convert ----------------
__global__ void cvt_f32_bf16(const float* __restrict__ src, unsigned short* __restrict__ dst, int n4) {
    int stride = gridDim.x * blockDim.x;
    for (int i = blockIdx.x * blockDim.x + threadIdx.x; i < n4; i += stride) {
        float4 v = ((const float4*)src)[i];
        ushort4v o;
        o.x = f2b(v.x); o.y = f2b(v.y); o.z = f2b(v.z); o.w = f2b(v.w);
        ((ushort4v*)dst)[i] = o;
    }
}

// ---------------- RoPE in-place on q,k of qkv buffer [B][T][3][H][D] bf16 ----------------
__global__ void rope_kernel(unsigned short* __restrict__ qkv) {
    int tid = blockIdx.x * blockDim.x + threadIdx.x;  // B*T*H*64 = 4194304
    int i = tid & 63;
    int h = (tid >> 6) & 15;
    int t = (tid >> 10) & 2047;
    int b = tid >> 21;
    float inv = __expf((float)i * -0.14391156608f);   // -ln(10000)/64
    float ang = (float)t * inv;
    float sn = sinf(ang), cs = cosf(ang);
    size_t base0 = ((size_t)(((b << 11) + t) * 3)) << 11;  // *(3*H*D=6144) flat, in elems
#pragma unroll
    for (int s = 0; s < 2; ++s) {
        size_t base = base0 + (size_t)s * 2048 + (h << 7);
        float v1 = b2f(qkv[base + i]);
        float v2 = b2f(qkv[base + 64 + i]);
        qkv[base + i]      = f2b(v1 * cs - v2 * sn);
        qkv[base + 64 + i] = f2b(v2 * cs + v1 * sn);
    }
}

// ---------------- bf16 NT GEMM: C[M][N] = A[M][K] * B[N][K]^T ----------------
// 128x128 tile, BK=64, 4 waves (2x2), global_load_lds staging with row-XOR swizzle.
template<int OUT_BF16>
__global__ __launch_bounds__(256) void gemm_nt(const unsigned short* __restrict__ A,
                                               const unsigned short* __restrict__ B,
                                               void* __restrict__ Cout,
                                               int N, int K) {
    constexpr int BK = 64;
    __shared__ unsigned short lA[128 * BK];
    __shared__ unsigned short lB[128 * BK];
    int tid = threadIdx.x;
    int lane = tid & 63, w = tid >> 6;
    int wr = w >> 1, wc = w & 1;
    int col = lane & 15, lg = lane >> 4;
    int rowBase = blockIdx.y * 128;
    int colBase = blockIdx.x * 128;
    f32x4 acc[4][4];
#pragma unroll
    for (int m = 0; m < 4; m++)
#pragma unroll
        for (int n = 0; n < 4; n++) acc[m][n] = (f32x4){0.f, 0.f, 0.f, 0.f};

    int rowS[4], scb[4];
#pragma unroll
    for (int it = 0; it < 4; ++it) {
        int d = it * 4096 + tid * 16;   // dest linear byte in tile (rows of 128B)
        int row = d >> 7;
        int cb = d & 127;
        rowS[it] = row;
        scb[it] = cb ^ ((row & 7) << 4);  // pre-swizzled source column byte
    }

    for (int kk = 0; kk < K; kk += BK) {
        __syncthreads();
#pragma unroll
        for (int it = 0; it < 4; ++it) {
            const char* srcA = (const char*)A + ((size_t)(rowBase + rowS[it]) * K + kk) * 2 + scb[it];
            const char* srcB = (const char*)B + ((size_t)(colBase + rowS[it]) * K + kk) * 2 + scb[it];
            char* dA = (char*)lA + it * 4096 + w * 1024;
            char* dB = (char*)lB + it * 4096 + w * 1024;
            GLOAD16(srcA, dA);
            GLOAD16(srcB, dB);
        }
        __syncthreads();
#pragma unroll
        for (int kc = 0; kc < 2; ++kc) {
            int cbyte = kc * 64 + 16 * lg;
            short8 af[4], bf[4];
#pragma unroll
            for (int m = 0; m < 4; m++) {
                int row = wr * 64 + m * 16 + col;
                af[m] = *(const short8*)((const char*)lA + row * 128 + (cbyte ^ ((row & 7) << 4)));
            }
#pragma unroll
            for (int n = 0; n < 4; n++) {
                int row = wc * 64 + n * 16 + col;
                bf[n] = *(const short8*)((const char*)lB + row * 128 + (cbyte ^ ((row & 7) << 4)));
            }
#pragma unroll
            for (int m = 0; m < 4; m++)
#pragma unroll
                for (int n = 0; n < 4; n++)
                    acc[m][n] = __builtin_amdgcn_mfma_f32_16x16x32_bf16(af[m], bf[n], acc[m][n], 0, 0, 0);
        }
    }
    int rbase = 4 * lg;
#pragma unroll
    for (int m = 0; m < 4; m++)
#pragma unroll
        for (int reg = 0; reg < 4; ++reg) {
            int r = rowBase + wr * 64 + m * 16 + rbase + reg;
#pragma unroll
            for (int n = 0; n < 4; n++) {
                int c = colBase + wc * 64 + n * 16 + col;
                float v = acc[m][n][reg];
                if (OUT_BF16) ((unsigned short*)Cout)[(size_t)r * N + c] = f2b(v);
                else          ((float*)Cout)[(size_t)r * N + c] = v;
            }
        }
}

// ---------------- fused causal flash attention ----------------
// qkv: [B][T][3][H][D] bf16 (RoPE already applied). out: [B][H][T][D] bf16.
// Block: 256 threads = 4 waves, 64 q-rows (16 per wave). KV tiles of 64.
__global__ __launch_bounds__(256) void attn_fused(const unsigned short* __restrict__ qkv,
                                                  unsigned short* __restrict__ out) {
    constexpr int T = 2048, H = 16;
    __shared__ unsigned short Kl[64 * 128];   // linear, XOR-swizzled via source
    __shared__ unsigned short Vt[128 * 64];   // transposed V, XOR-swizzled columns
    __shared__ unsigned short Pl[64][72];     // P tiles, padded rows (144B = 16*9)
    int tid = threadIdx.x, lane = tid & 63, w = tid >> 6;
    int col = lane & 15, lg = lane >> 4;
    int qt = blockIdx.x & 31;
    int h = (blockIdx.x >> 5) & 15;
    int b = blockIdx.x >> 9;
    int qbase = qt * 64;

    // Q fragments (held in registers for whole kernel)
    short8 qf[4];
    {
        int t = qbase + w * 16 + col;
        const unsigned short* qp = qkv + ((size_t)(b * T + t) * 3) * 2048 + h * 128;
#pragma unroll
        for (int kc = 0; kc < 4; kc++) qf[kc] = *(const short8*)(qp + kc * 32 + 8 * lg);
    }
    f32x4 O[8];
#pragma unroll
    for (int n = 0; n < 8; n++) O[n] = (f32x4){0.f, 0.f, 0.f, 0.f};
    float mi[4] = {-1e30f, -1e30f, -1e30f, -1e30f};
    float li[4] = {0.f, 0.f, 0.f, 0.f};
    const float scale = 0.08838834764831845f;  // 1/sqrt(128)

    int nkv = qt + 1;
    for (int kv = 0; kv < nkv; ++kv) {
        int kvbase = kv * 64;
        __syncthreads();
        // stage K tile [64][128] via global_load_lds, source-side XOR swizzle
#pragma unroll
        for (int it = 0; it < 4; ++it) {
            int dby = it * 4096 + tid * 16;
            int row = dby >> 8;                  // 256B rows
            int cb = dby & 255;
            int scb = cb ^ ((row & 7) << 4);
            const char* src = (const char*)(qkv + ((size_t)(b * T + kvbase + row) * 3 + 1) * 2048 + h * 128) + scb;
            char* dst = (char*)Kl + it * 4096 + w * 1024;
            GLOAD16(src, dst);
        }
        // stage V transposed + swizzled: Vt[d][r ^ f(d)], f(d)=8*((d+(d>>3))&7)
#pragma unroll
        for (int it = 0; it < 4; ++it) {
            int chunk = it * 256 + tid;
            int r = chunk >> 4;
            int c = (chunk & 15) << 3;
            const unsigned short* vp = qkv + ((size_t)(b * T + kvbase + r) * 3 + 2) * 2048 + h * 128 + c;
            short8 vv = *(const short8*)vp;
#pragma unroll
            for (int j = 0; j < 8; j++) {
                int d = c + j;
                Vt[d * 64 + (r ^ (((d + (d >> 3)) & 7) << 3))] = (unsigned short)vv[j];
            }
        }
        __syncthreads();
        // S = Q K^T for this wave's 16 rows x 64 cols
        f32x4 s[4];
#pragma unroll
        for (int ct = 0; ct < 4; ct++) s[ct] = (f32x4){0.f, 0.f, 0.f, 0.f};
#pragma unroll
        for (int ct = 0; ct < 4; ct++) {
            int rowK = ct * 16 + col;
#pragma unroll
            for (int kc = 0; kc < 4; kc++) {
                int cbyte = kc * 64 + 16 * lg;
                short8 kf = *(const short8*)((const char*)Kl + rowK * 256 + (cbyte ^ ((rowK & 7) << 4)));
                s[ct] = __builtin_amdgcn_mfma_f32_16x16x32_bf16(qf[kc], kf, s[ct], 0, 0, 0);
            }
        }
        // scale + causal mask (only diagonal tile needs it)
        float sv[4][4];
        bool diag = (kv == qt);
#pragma unroll
        for (int ct = 0; ct < 4; ct++)
#pragma unroll
            for (int reg = 0; reg < 4; reg++) {
                float v = s[ct][reg] * scale;
                if (diag) {
                    int qi = w * 16 + 4 * lg + reg;
                    int kj = ct * 16 + col;
                    if (kj > qi) v = -1e30f;
                }
                sv[ct][reg] = v;
            }
        // online softmax: row reductions across 16-lane groups
        float esc[4];
#pragma unroll
        for (int reg = 0; reg < 4; reg++) {
            float v = fmaxf(fmaxf(sv[0][reg], sv[1][reg]), fmaxf(sv[2][reg], sv[3][reg]));
            v = fmaxf(v, __shfl_xor(v, 1));
            v = fmaxf(v, __shfl_xor(v, 2));
            v = fmaxf(v, __shfl_xor(v, 4));
            v = fmaxf(v, __shfl_xor(v, 8));
            float mn = fmaxf(mi[reg], v);
            esc[reg] = __expf(mi[reg] - mn);
            mi[reg] = mn;
        }
        unsigned short pb[4][4];
        float rsum[4] = {0.f, 0.f, 0.f, 0.f};
#pragma unroll
        for (int ct = 0; ct < 4; ct++)
#pragma unroll
            for (int reg = 0; reg < 4; reg++) {
                float p = __expf(sv[ct][reg] - mi[reg]);
                rsum[reg] += p;
                pb[ct][reg] = f2b(p);
            }
#pragma unroll
        for (int reg = 0; reg < 4; reg++) {
            float v = rsum[reg];
            v += __shfl_xor(v, 1);
            v += __shfl_xor(v, 2);
            v += __shfl_xor(v, 4);
            v += __shfl_xor(v, 8);
            li[reg] = li[reg] * esc[reg] + v;
        }
#pragma unroll
        for (int n = 0; n < 8; n++)
#pragma unroll
            for (int reg = 0; reg < 4; reg++) O[n][reg] *= esc[reg];
        // write P (C-layout) into LDS for A-fragment relayout
#pragma unroll
        for (int ct = 0; ct < 4; ct++)
#pragma unroll
            for (int reg = 0; reg < 4; reg++)
                Pl[w * 16 + 4 * lg + reg][ct * 16 + col] = pb[ct][reg];
        __syncthreads();
        // O += P V
#pragma unroll
        for (int c = 0; c < 2; c++) {
            short8 pf = *(const short8*)&Pl[w * 16 + col][c * 32 + 8 * lg];
#pragma unroll
            for (int n = 0; n < 8; n++) {
                int d = n * 16 + col;
                int e = (c * 32 + 8 * lg) ^ (((d + (d >> 3)) & 7) << 3);
                short8 vf = *(const short8*)&Vt[d * 64 + e];
                O[n] = __builtin_amdgcn_mfma_f32_16x16x32_bf16(pf, vf, O[n], 0, 0, 0);
            }
        }
    }
    // epilogue: O /= l, store bf16 to [B][H][T][D]
#pragma unroll
    for (int reg = 0; reg < 4; reg++) li[reg] = 1.0f / li[reg];
#pragma unroll
    for (int n = 0; n < 8; n++)
#pragma unroll
        for (int reg = 0; reg < 4; reg++) {
            int t = qbase + w * 16 + 4 * lg + reg;
            out[((size_t)(b * H + h) * T + t) * 128 + n * 16 + col] = f2b(O[n][reg] * li[reg]);
        }
}

// ---------------- launch ----------------
extern "C" void kernel_launch(void* const* d_in, const int* in_sizes, int n_in,
                              void* d_out, int out_size, void* d_ws, size_t ws_size,
                              hipStream_t stream) {
    const float* x      = (const float*)d_in[0];
    const float* w_qkv  = (const float*)d_in[1];
    const float* w_proj = (const float*)d_in[2];
    const int B = 2, T = 2048, C = 2048, H = 16;
    const int M = B * T;        // 4096
    const int F = 3 * C;        // 6144

    // ws layout (bf16): r1 = x / later attn-out (M*C), r2 = w_qkv / later w_proj (F*C), r3 = qkv (M*F)
    size_t need = ((size_t)M * C + (size_t)F * C + (size_t)M * F) * 2;
    if (ws_size < need) return;  // fail loudly via validation rather than corrupt memory
    unsigned short* r1 = (unsigned short*)d_ws;
    unsigned short* r2 = r1 + (size_t)M * C;
    unsigned short* r3 = r2 + (size_t)F * C;

    // 1. convert x, w_qkv to bf16
    cvt_f32_bf16<<<2048, 256, 0, stream>>>(x, r1, (M * C) / 4);
    cvt_f32_bf16<<<2048, 256, 0, stream>>>(w_qkv, r2, (F * C) / 4);
    // 2. qkv = x @ w_qkv^T  (bf16 out)
    gemm_nt<1><<<dim3(F / 128, M / 128), 256, 0, stream>>>(r1, r2, (void*)r3, F, C);
    // 3. RoPE in place on q,k
    rope_kernel<<<(B * T * H * 64) / 256, 256, 0, stream>>>(r3);
    // 4. convert w_proj into r2 (w_qkv no longer needed)
    cvt_f32_bf16<<<2048, 256, 0, stream>>>(w_proj, r2, (C * C) / 4);
    // 5. attention -> r1 (x no longer needed); layout [B][H][T][D] == reference's buggy reshape
    attn_fused<<<B * H * (T / 64), 256, 0, stream>>>(r3, r1);
    // 6. out = attn @ w_proj^T (fp32 out)
    gemm_nt<0><<<dim3(C / 128, M / 128), 256, 0, stream>>>(r1, r2, d_out, C, C);
}